// Round 3
// baseline (89.049 us; speedup 1.0000x reference)
//
#include <hip/hip_runtime.h>
#include <math.h>

#define BATCH   4
#define NPTS    8192
#define THREADS 256
#define TILE    128                       // P tile: 128 rows(gts) x 128 cols(preds)
#define NTILES  (NPTS / TILE)             // 64
#define PATCH   8                         // per-thread 8x8 pairs
#define NMINS   (2 * BATCH * NPTS)        // 65536 mins (rows: mins2 gts | cols: mins1 preds)

// ws layout: [0,512K) G4; [512K,1M) P4; [1M,1.25M) uint mins
#define WS_P4_OFF  (BATCH * NPTS * sizeof(float4))
#define WS_MIN_OFF (2 * BATCH * NPTS * sizeof(float4))
#define INF_BITS   0x7F800000u

// G4[b][n] = (-2gx,-2gy,-2gz,|g|^2)  (row side, gts)
// P4[b][m] = ( px,  py,  pz, |p|^2)  (col side, preds)
__global__ __launch_bounds__(THREADS) void chamfer_pre(const float* __restrict__ preds,
                                                       const float* __restrict__ gts,
                                                       float4* __restrict__ G4,
                                                       float4* __restrict__ P4,
                                                       unsigned int* __restrict__ wsmin) {
    int i = blockIdx.x * THREADS + threadIdx.x;        // 0..65535
    int side = i >> 15;                                // 0: gts, 1: preds
    int t = i & 32767;
    if (side == 0) {
        float x = gts[3 * t], y = gts[3 * t + 1], z = gts[3 * t + 2];
        G4[t] = make_float4(-2.0f * x, -2.0f * y, -2.0f * z, fmaf(x, x, fmaf(y, y, z * z)));
    } else {
        float x = preds[3 * t], y = preds[3 * t + 1], z = preds[3 * t + 2];
        P4[t] = make_float4(x, y, z, fmaf(x, x, fmaf(y, y, z * z)));
    }
    wsmin[i] = INF_BITS;
}

__global__ __launch_bounds__(THREADS) void chamfer_main(const float4* __restrict__ G4,
                                                        const float4* __restrict__ P4,
                                                        unsigned int* __restrict__ wsmin) {
    const int tileN = blockIdx.x;          // row tile (gts)
    const int tileM = blockIdx.y;          // col tile (preds)
    const int b     = blockIdx.z;

    __shared__ float4 G4L[TILE];
    __shared__ float4 P4L[TILE];
    __shared__ unsigned int rowL[TILE];
    __shared__ unsigned int colL[TILE];

    const int t  = threadIdx.x;
    const int tx = t & 15;                 // col group
    const int ty = t >> 4;                 // row group

    // stage tile points + init LDS mins
    if (t < TILE) {
        G4L[t] = G4[(size_t)b * NPTS + tileN * TILE + t];
        rowL[t] = INF_BITS;
    } else {
        P4L[t - TILE] = P4[(size_t)b * NPTS + tileM * TILE + (t - TILE)];
        colL[t - TILE] = INF_BITS;
    }
    __syncthreads();

    float gx[PATCH], gy[PATCH], gz[PATCH], gw[PATCH];
    float px[PATCH], py[PATCH], pz[PATCH], pw[PATCH];
    float rmin[PATCH], cmin[PATCH];
#pragma unroll
    for (int i = 0; i < PATCH; ++i) {
        float4 g = G4L[ty + 16 * i];       // 4 addrs/wave -> broadcast, conflict-free
        gx[i] = g.x; gy[i] = g.y; gz[i] = g.z; gw[i] = g.w;
        rmin[i] = INFINITY;
    }
#pragma unroll
    for (int j = 0; j < PATCH; ++j) {
        float4 p = P4L[tx + 16 * j];       // 16 addrs/wave, 16B stride -> 2-way, free
        px[j] = p.x; py[j] = p.y; pz[j] = p.z; pw[j] = p.w;
        cmin[j] = INFINITY;
    }

    // 64 pairs: t = rp - 2 g.p ; u = t + rg = P
#pragma unroll
    for (int j = 0; j < PATCH; ++j) {
#pragma unroll
        for (int i = 0; i < PATCH; ++i) {
            float s = fmaf(gz[i], pz[j], pw[j]);
            s = fmaf(gy[i], py[j], s);
            s = fmaf(gx[i], px[j], s);
            float u = s + gw[i];
            rmin[i] = fminf(rmin[i], s);   // rg added once at the end
            cmin[j] = fminf(cmin[j], u);
        }
    }

#pragma unroll
    for (int i = 0; i < PATCH; ++i) {
        float v = fmaxf(rmin[i] + gw[i], 0.0f);     // clamp keeps uint order valid
        atomicMin(&rowL[ty + 16 * i], __float_as_uint(v));
    }
#pragma unroll
    for (int j = 0; j < PATCH; ++j) {
        float v = fmaxf(cmin[j], 0.0f);
        atomicMin(&colL[tx + 16 * j], __float_as_uint(v));
    }
    __syncthreads();

    // rows: mins2 (per gt) at [0, B*NPTS); cols: mins1 (per pred) at [B*NPTS, 2*B*NPTS)
    if (t < TILE) {
        atomicMin(&wsmin[(size_t)b * NPTS + tileN * TILE + t], rowL[t]);
    } else {
        atomicMin(&wsmin[(size_t)(BATCH + b) * NPTS + tileM * TILE + (t - TILE)], colL[t - TILE]);
    }
}

__global__ __launch_bounds__(THREADS) void chamfer_reduce(const unsigned int* __restrict__ wsmin,
                                                          float* __restrict__ out) {
    const float4* __restrict__ v = (const float4*)wsmin;  // bits are valid floats (>=0)
    float s = 0.0f;
    int i = threadIdx.x;
#pragma unroll 4
    for (int it = 0; it < NMINS / 4 / THREADS; ++it, i += THREADS) {
        float4 a = v[i];
        s += (a.x + a.y) + (a.z + a.w);
    }
    for (int off = 32; off; off >>= 1) s += __shfl_down(s, off, 64);
    __shared__ float sm[THREADS / 64];
    if ((threadIdx.x & 63) == 0) sm[threadIdx.x >> 6] = s;
    __syncthreads();
    if (threadIdx.x == 0) {
        float tt = 0.0f;
#pragma unroll
        for (int w = 0; w < THREADS / 64; ++w) tt += sm[w];
        out[0] = tt / (float)NPTS;  // sum(mins1)/M + sum(mins2)/N, M=N=NPTS
    }
}

extern "C" void kernel_launch(void* const* d_in, const int* in_sizes, int n_in,
                              void* d_out, int out_size, void* d_ws, size_t ws_size,
                              hipStream_t stream) {
    const float* preds = (const float*)d_in[0];
    const float* gts   = (const float*)d_in[1];
    float* out = (float*)d_out;
    float4* G4 = (float4*)d_ws;
    float4* P4 = (float4*)((char*)d_ws + WS_P4_OFF);
    unsigned int* wsmin = (unsigned int*)((char*)d_ws + WS_MIN_OFF);

    chamfer_pre<<<NMINS / THREADS, THREADS, 0, stream>>>(preds, gts, G4, P4, wsmin);

    dim3 grid(NTILES, NTILES, BATCH);
    chamfer_main<<<grid, THREADS, 0, stream>>>(G4, P4, wsmin);

    chamfer_reduce<<<1, THREADS, 0, stream>>>(wsmin, out);
}

// Round 5
// 55.938 us; speedup vs baseline: 1.5919x; 1.5919x over previous
//
#include <hip/hip_runtime.h>
#include <math.h>

#define BATCH    4
#define NPTS     8192
#define THREADS  256
#define RTHREADS 1024
#define ROWTILE  128
#define COLTILE  128
#define NCT      8                        // col tiles per block
#define COLSUPER (COLTILE * NCT)          // 1024
#define NROWB    (NPTS / ROWTILE)         // 64
#define NCOLB    (NPTS / COLSUPER)        // 8
#define NMINS    (2 * BATCH * NPTS)       // 65536 (rows: per-gt | cols: per-pred)

// ws layout: [0,512K) G4; [512K,1M) P4; [1M,1.25M) uint mins
#define WS_P4_OFF  (BATCH * NPTS * sizeof(float4))
#define WS_MIN_OFF (2 * BATCH * NPTS * sizeof(float4))
#define INF_BITS   0x7F800000u

// G4[b][n] = (-2gx,-2gy,-2gz,|g|^2)  (rows, gts)
// P4[b][m] = ( px,  py,  pz, |p|^2)  (cols, preds)
__global__ __launch_bounds__(THREADS) void chamfer_pre(const float* __restrict__ preds,
                                                       const float* __restrict__ gts,
                                                       float4* __restrict__ G4,
                                                       float4* __restrict__ P4,
                                                       unsigned int* __restrict__ wsmin) {
    int i = blockIdx.x * THREADS + threadIdx.x;        // 0..65535
    int side = i >> 15;
    int t = i & 32767;
    if (side == 0) {
        float x = gts[3 * t], y = gts[3 * t + 1], z = gts[3 * t + 2];
        G4[t] = make_float4(-2.0f * x, -2.0f * y, -2.0f * z, fmaf(x, x, fmaf(y, y, z * z)));
    } else {
        float x = preds[3 * t], y = preds[3 * t + 1], z = preds[3 * t + 2];
        P4[t] = make_float4(x, y, z, fmaf(x, x, fmaf(y, y, z * z)));
    }
    wsmin[i] = INF_BITS;
}

__global__ __launch_bounds__(THREADS) void chamfer_main(const float4* __restrict__ G4,
                                                        const float4* __restrict__ P4,
                                                        unsigned int* __restrict__ wsmin) {
    const int tileN = blockIdx.x;          // row tile
    const int csup  = blockIdx.y;          // col super-tile (1024 cols)
    const int b     = blockIdx.z;

    __shared__ float4 GL[ROWTILE];
    __shared__ float4 PL[COLTILE];
    __shared__ float  colbuf[4][COLTILE];

    const int t = threadIdx.x, tx = t & 15, ty = t >> 4, wv = t >> 6;
    const size_t gbase = (size_t)b * NPTS;

    // prologue: stage G rows (threads 0..127) + first P tile (threads 128..255)
    if (t < ROWTILE) {
        GL[t] = G4[gbase + (size_t)tileN * ROWTILE + t];
    } else {
        int j = t - (THREADS - COLTILE);
        PL[j] = P4[gbase + (size_t)csup * COLSUPER + j];
    }
    __syncthreads();

    float gx[8], gy[8], gz[8], gw[8], rmin[8];
#pragma unroll
    for (int i = 0; i < 8; ++i) {
        float4 g = GL[ty + 16 * i];        // 16-lane broadcast, conflict-free
        gx[i] = g.x; gy[i] = g.y; gz[i] = g.z; gw[i] = g.w;
        rmin[i] = INFINITY;
    }

    for (int ct = 0; ct < NCT; ++ct) {
        // PL currently holds tile ct; pull my 8 cols into regs
        float px[8], py[8], pz[8], pw[8], cmin[8];
#pragma unroll
        for (int j = 0; j < 8; ++j) {
            float4 p = PL[tx + 16 * j];    // 2-way at worst -> free
            px[j] = p.x; py[j] = p.y; pz[j] = p.z; pw[j] = p.w;
            cmin[j] = INFINITY;
        }
        __syncthreads();                   // PL consumed; colbuf(ct-1) consumed

        // pipeline: stage tile ct+1 (threads 128..255) while everyone computes
        if (ct + 1 < NCT && t >= THREADS - COLTILE) {
            int j = t - (THREADS - COLTILE);
            PL[j] = P4[gbase + (size_t)csup * COLSUPER + (size_t)(ct + 1) * COLTILE + j];
        }

        // 8x8 patch: u = |g-p|^2 (expanded form); min3-friendly pairs
#pragma unroll
        for (int j = 0; j < 8; j += 2) {
#pragma unroll
            for (int i = 0; i < 8; i += 2) {
                float u00, u01, u10, u11;
                { float s = fmaf(gz[i  ], pz[j  ], pw[j  ]); s = fmaf(gy[i  ], py[j  ], s); s = fmaf(gx[i  ], px[j  ], s); u00 = s + gw[i  ]; }
                { float s = fmaf(gz[i+1], pz[j  ], pw[j  ]); s = fmaf(gy[i+1], py[j  ], s); s = fmaf(gx[i+1], px[j  ], s); u01 = s + gw[i+1]; }
                { float s = fmaf(gz[i  ], pz[j+1], pw[j+1]); s = fmaf(gy[i  ], py[j+1], s); s = fmaf(gx[i  ], px[j+1], s); u10 = s + gw[i  ]; }
                { float s = fmaf(gz[i+1], pz[j+1], pw[j+1]); s = fmaf(gy[i+1], py[j+1], s); s = fmaf(gx[i+1], px[j+1], s); u11 = s + gw[i+1]; }
                rmin[i  ] = fminf(fminf(rmin[i  ], u00), u10);   // -> v_min3
                rmin[i+1] = fminf(fminf(rmin[i+1], u01), u11);
                cmin[j  ] = fminf(fminf(cmin[j  ], u00), u01);
                cmin[j+1] = fminf(fminf(cmin[j+1], u10), u11);
            }
        }

        // col reduce: xor 16,32 collapses ty within wave; plain stores (no atomics)
#pragma unroll
        for (int j = 0; j < 8; ++j) {
            float c = cmin[j];
            c = fminf(c, __shfl_xor(c, 16, 64));
            c = fminf(c, __shfl_xor(c, 32, 64));
            if ((t & 63) < 16) colbuf[wv][tx + 16 * j] = c;
        }
        __syncthreads();
        if (t < COLTILE) {
            float v = fminf(fminf(colbuf[0][t], colbuf[1][t]),
                            fminf(colbuf[2][t], colbuf[3][t]));
            v = fmaxf(v, 0.0f);            // keep uint ordering valid
            atomicMin(&wsmin[(size_t)(BATCH + b) * NPTS + (size_t)csup * COLSUPER + (size_t)ct * COLTILE + t],
                      __float_as_uint(v)); // exact & deterministic
        }
    }

    // row reduce: xor 1,2,4,8 collapses the 16-lane tx group; once per block
#pragma unroll
    for (int i = 0; i < 8; ++i) {
        float r = rmin[i];
        r = fminf(r, __shfl_xor(r, 1, 64));
        r = fminf(r, __shfl_xor(r, 2, 64));
        r = fminf(r, __shfl_xor(r, 4, 64));
        r = fminf(r, __shfl_xor(r, 8, 64));
        if (tx == 0) {
            float v = fmaxf(r, 0.0f);
            atomicMin(&wsmin[(size_t)b * NPTS + (size_t)tileN * ROWTILE + ty + 16 * i],
                      __float_as_uint(v));
        }
    }
}

__global__ __launch_bounds__(RTHREADS) void chamfer_reduce(const unsigned int* __restrict__ wsmin,
                                                           float* __restrict__ out) {
    const float4* __restrict__ v = (const float4*)wsmin;  // bits are valid floats (>=0)
    float s = 0.0f;
    int i = threadIdx.x;
#pragma unroll
    for (int it = 0; it < NMINS / 4 / RTHREADS; ++it, i += RTHREADS) {
        float4 a = v[i];
        s += (a.x + a.y) + (a.z + a.w);
    }
    for (int off = 32; off; off >>= 1) s += __shfl_down(s, off, 64);
    __shared__ float sm[RTHREADS / 64];
    if ((threadIdx.x & 63) == 0) sm[threadIdx.x >> 6] = s;
    __syncthreads();
    if (threadIdx.x == 0) {
        float tt = 0.0f;
#pragma unroll
        for (int w = 0; w < RTHREADS / 64; ++w) tt += sm[w];
        out[0] = tt / (float)NPTS;  // sum(mins1)/M + sum(mins2)/N, M=N=NPTS
    }
}

extern "C" void kernel_launch(void* const* d_in, const int* in_sizes, int n_in,
                              void* d_out, int out_size, void* d_ws, size_t ws_size,
                              hipStream_t stream) {
    const float* preds = (const float*)d_in[0];
    const float* gts   = (const float*)d_in[1];
    float* out = (float*)d_out;
    float4* G4 = (float4*)d_ws;
    float4* P4 = (float4*)((char*)d_ws + WS_P4_OFF);
    unsigned int* wsmin = (unsigned int*)((char*)d_ws + WS_MIN_OFF);

    chamfer_pre<<<NMINS / THREADS, THREADS, 0, stream>>>(preds, gts, G4, P4, wsmin);

    dim3 grid(NROWB, NCOLB, BATCH);
    chamfer_main<<<grid, THREADS, 0, stream>>>(G4, P4, wsmin);

    chamfer_reduce<<<1, RTHREADS, 0, stream>>>(wsmin, out);
}